// Round 8
// baseline (5077.283 us; speedup 1.0000x reference)
//
#include <hip/hip_runtime.h>
#include <hip/hip_bf16.h>
#include <hip/hip_fp16.h>

#define DZ 128
#define DB 32
#define DSIN 32
#define DX 64
#define NB 64
#define TT 4096

typedef short v8s __attribute__((ext_vector_type(8)));
typedef float v4f __attribute__((ext_vector_type(4)));
typedef _Float16 v2h __attribute__((ext_vector_type(2)));

__device__ __forceinline__ short f2bf(float f) {
  __hip_bfloat16 h = __float2bfloat16(f);
  return *reinterpret_cast<short*>(&h);
}

// pack two f32 -> packed bf16 dword, single instruction
__device__ __forceinline__ unsigned cvt_pk_bf16(float lo, float hi) {
  unsigned r;
  asm volatile("v_cvt_pk_bf16_f32 %0, %1, %2" : "=v"(r) : "v"(lo), "v"(hi));
  return r;
}

__device__ __forceinline__ v2h pk2h(float a, float b) {
  return __builtin_bit_cast(v2h, __builtin_amdgcn_cvt_pkrtz(a, b));
}
__device__ __forceinline__ float fdot2(v2h a, v2h b, float c) {
  return __builtin_amdgcn_fdot2(a, b, c, false);
}

// --- kernel 0: WCd[i] = sum_{j != i} AW[i][j] * (sum_k alphas[k]*clip[j][k]) ---
__global__ void k_prep(const float* __restrict__ AW, const float* __restrict__ alphas,
                       const float* __restrict__ clip, float* __restrict__ WCd) {
  __shared__ float cd[DZ];
  int j = threadIdx.x;
  float s = 0.f;
  for (int k = 0; k < DB; ++k) s = fmaf(alphas[k], clip[j * DB + k], s);
  cd[j] = s;
  __syncthreads();
  float acc = 0.f;
  for (int jj = 0; jj < DZ; ++jj)
    if (jj != j) acc = fmaf(AW[j * DZ + jj], cd[jj], acc);
  WCd[j] = acc;
}

// --- kernel 1: U[t][i] = h[i] - WCd[i] + sum_s C[i][s]*inp[t][s] (t-major) ---
__global__ void k_u(const float* __restrict__ inp, const float* __restrict__ h,
                    const float* __restrict__ C, const float* __restrict__ WCd,
                    float* __restrict__ U) {
  int gid = blockIdx.x * blockDim.x + threadIdx.x;
  int t = gid >> 7, i = gid & 127;
  float u = h[i] - WCd[i];
  const float4* c4 = (const float4*)(C + i * DSIN);
  const float4* i4 = (const float4*)(inp + (size_t)t * DSIN);
#pragma unroll
  for (int s = 0; s < 8; ++s) {
    float4 cv = c4[s], iv = i4[s];
    u = fmaf(cv.x, iv.x, u);
    u = fmaf(cv.y, iv.y, u);
    u = fmaf(cv.z, iv.z, u);
    u = fmaf(cv.w, iv.w, u);
  }
  U[gid] = u;
}

// --- kernel 2: sequential scan, ONE BATCH PER WAVE, no barriers.
// Lane l owns dims (2l, 2l+1). g exchange: intra-wave LDS write+readback
// (DS pipe is in-order per wave; waves are lockstep -> no barrier, no dbuf).
// W/theta/clip/alpha/g in packed f16; all accumulation via v_dot2_f32_f16 (f32 acc).
// 8 blocks x 8 waves = 2 independent waves/SIMD -> TLP hides latency. ---
__global__ __launch_bounds__(512, 2) void k_scan(
    const float* __restrict__ z0, const float* __restrict__ AW,
    const float* __restrict__ thetas, const float* __restrict__ alphas,
    const float* __restrict__ clip, const float* __restrict__ U,
    unsigned* __restrict__ Z32) {
  __shared__ unsigned gsh[8][64];  // per-wave 256 B
  const int wv = threadIdx.x >> 6, l = threadIdx.x & 63;
  const int b = blockIdx.x * 8 + wv;
  const int r0 = 2 * l, r1 = r0 + 1;

  // W rows r0,r1 as packed f16 pairs (cols 2j,2j+1); diagonal zeroed branchlessly
  v2h w0[64], w1[64];
#pragma unroll
  for (int j = 0; j < 64; ++j) {
    float2 a0 = *(const float2*)(AW + (size_t)r0 * DZ + 2 * j);
    float2 a1 = *(const float2*)(AW + (size_t)r1 * DZ + 2 * j);
    float x0 = (j == l) ? 0.f : a0.x;  // col 2j   == r0 iff j==l
    float y1 = (j == l) ? 0.f : a1.y;  // col 2j+1 == r1 iff j==l
    w0[j] = pk2h(x0, a0.y);
    w1[j] = pk2h(a1.x, y1);
  }
  const float ad0 = AW[(size_t)r0 * DZ + r0], ad1 = AW[(size_t)r1 * DZ + r1];

  v2h th0[16], th1[16], nc0[16], nc1[16];
  int al[16];  // packed f16 (-0.82*alpha), wave-uniform -> SGPR via readfirstlane
#pragma unroll
  for (int k = 0; k < 16; ++k) {
    th0[k] = pk2h(thetas[r0 * DB + 2 * k], thetas[r0 * DB + 2 * k + 1]);
    th1[k] = pk2h(thetas[r1 * DB + 2 * k], thetas[r1 * DB + 2 * k + 1]);
    nc0[k] = pk2h(-clip[r0 * DB + 2 * k], -clip[r0 * DB + 2 * k + 1]);
    nc1[k] = pk2h(-clip[r1 * DB + 2 * k], -clip[r1 * DB + 2 * k + 1]);
    al[k] = __builtin_amdgcn_readfirstlane(__builtin_bit_cast(
        int, pk2h(-0.82f * alphas[2 * k], -0.82f * alphas[2 * k + 1])));
  }

  float zA = z0[b * DZ + r0], zB = z0[b * DZ + r1];
  float2 uc = *(const float2*)(U + r0);  // t = 0
  unsigned* zp = Z32 + (size_t)b * 64 + l;
  const v2h zero2 = pk2h(0.f, 0.f);
  const uint4* g4 = (const uint4*)gsh[wv];

#pragma unroll 1
  for (int t = 0; t < TT; ++t) {
    float2 un = *(const float2*)(U + (size_t)((t + 1) & (TT - 1)) * DZ + r0);
    // basis: g_r = sum_k (-0.82 a_k) * clamp(z_r - th_rk, -c_rk, 0), packed f16
    v2h za2 = pk2h(zA, zA), zb2 = pk2h(zB, zB);
    float g0 = 0.f, g1 = 0.f;
#pragma unroll
    for (int k = 0; k < 16; ++k) {
      v2h d0 = __builtin_elementwise_min(
          __builtin_elementwise_max(za2 - th0[k], nc0[k]), zero2);
      v2h d1 = __builtin_elementwise_min(
          __builtin_elementwise_max(zb2 - th1[k], nc1[k]), zero2);
      g0 = fdot2(__builtin_bit_cast(v2h, al[k]), d0, g0);
      g1 = fdot2(__builtin_bit_cast(v2h, al[k]), d1, g1);
    }
    // intra-wave exchange (no barrier: single-wave lockstep + in-order DS pipe)
    gsh[wv][l] = __builtin_bit_cast(unsigned, pk2h(g0, g1));
    // matvec rows r0,r1: 64 packed-f16 g dwords, broadcast reads, f32 acc
    float m0a = 0.f, m0b = 0.f, m1a = 0.f, m1b = 0.f;
#pragma unroll
    for (int r = 0; r < 16; ++r) {
      uint4 q = g4[r];
      v2h gA = __builtin_bit_cast(v2h, q.x), gB = __builtin_bit_cast(v2h, q.y);
      v2h gC = __builtin_bit_cast(v2h, q.z), gD = __builtin_bit_cast(v2h, q.w);
      m0a = fdot2(w0[4 * r + 0], gA, m0a);
      m1a = fdot2(w1[4 * r + 0], gA, m1a);
      m0b = fdot2(w0[4 * r + 1], gB, m0b);
      m1b = fdot2(w1[4 * r + 1], gB, m1b);
      m0a = fdot2(w0[4 * r + 2], gC, m0a);
      m1a = fdot2(w1[4 * r + 2], gC, m1a);
      m0b = fdot2(w0[4 * r + 3], gD, m0b);
      m1b = fdot2(w1[4 * r + 3], gD, m1b);
    }
    zA = fmaf(zA, ad0, (m0a + m0b) + uc.x);
    zB = fmaf(zB, ad1, (m1a + m1b) + uc.y);
    uc = un;
    zp[(size_t)t * (NB * 64)] = cvt_pk_bf16(zA, zB);  // coalesced dword store
  }
}

// --- kernel 3: out = Z(bf16, 262144x128) @ B_obs(128x64) via MFMA 16x16x32 bf16 ---
__global__ __launch_bounds__(256) void k_obs(const short* __restrict__ Z,
                                             const float* __restrict__ Bo,
                                             float* __restrict__ out) {
  const int lane = threadIdx.x & 63;
  const int wv = threadIdx.x >> 6;
  const int rl = lane & 15;  // A row / C col index
  const int g = lane >> 4;   // k-group

  v8s bfr[4][4];
#pragma unroll
  for (int nt = 0; nt < 4; ++nt) {
#pragma unroll
    for (int ks = 0; ks < 4; ++ks) {
      v8s f;
#pragma unroll
      for (int m = 0; m < 8; ++m) {
        int k = ks * 32 + g * 8 + m;
        f[m] = f2bf(Bo[k * DX + nt * 16 + rl]);
      }
      bfr[nt][ks] = f;
    }
  }

#pragma unroll
  for (int it = 0; it < 4; ++it) {
    const int r0 = blockIdx.x * 256 + it * 64 + wv * 16;
    const short* zrow = Z + (size_t)(r0 + rl) * DZ;
    v8s afr[4];
#pragma unroll
    for (int ks = 0; ks < 4; ++ks)
      afr[ks] = *(const v8s*)(zrow + ks * 32 + g * 8);
    v4f acc[4];
#pragma unroll
    for (int nt = 0; nt < 4; ++nt) acc[nt] = (v4f){0.f, 0.f, 0.f, 0.f};
#pragma unroll
    for (int nt = 0; nt < 4; ++nt) {
#pragma unroll
      for (int ks = 0; ks < 4; ++ks)
        acc[nt] = __builtin_amdgcn_mfma_f32_16x16x32_bf16(afr[ks], bfr[nt][ks], acc[nt], 0, 0, 0);
    }
#pragma unroll
    for (int nt = 0; nt < 4; ++nt) {
#pragma unroll
      for (int q = 0; q < 4; ++q)
        out[(size_t)(r0 + g * 4 + q) * DX + nt * 16 + rl] = acc[nt][q];
    }
  }
}

extern "C" void kernel_launch(void* const* d_in, const int* in_sizes, int n_in,
                              void* d_out, int out_size, void* d_ws, size_t ws_size,
                              hipStream_t stream) {
  const float* z0 = (const float*)d_in[0];
  const float* inp = (const float*)d_in[1];
  const float* AW = (const float*)d_in[2];
  const float* h = (const float*)d_in[3];
  const float* thetas = (const float*)d_in[4];
  const float* alphas = (const float*)d_in[5];
  const float* clip = (const float*)d_in[6];
  const float* C = (const float*)d_in[7];
  const float* Bo = (const float*)d_in[8];
  float* out = (float*)d_out;

  char* ws = (char*)d_ws;
  float* WCd = (float*)ws;                               // 512 B
  float* U = (float*)(ws + 1024);                        // TT*128 f32 = 2 MiB
  short* Z = (short*)(ws + 1024 + (size_t)TT * DZ * 4);  // TT*64*128 bf16 = 64 MiB

  k_prep<<<1, 128, 0, stream>>>(AW, alphas, clip, WCd);
  k_u<<<(TT * DZ) / 256, 256, 0, stream>>>(inp, h, C, WCd, U);
  k_scan<<<NB / 8, 512, 0, stream>>>(z0, AW, thetas, alphas, clip, U, (unsigned*)Z);
  k_obs<<<(TT * NB) / 256, 256, 0, stream>>>(Z, Bo, out);
}

// Round 9
// 3056.758 us; speedup vs baseline: 1.6610x; 1.6610x over previous
//
#include <hip/hip_runtime.h>
#include <hip/hip_bf16.h>
#include <hip/hip_fp16.h>

#define DZ 128
#define DB 32
#define DSIN 32
#define DX 64
#define NB 64
#define TT 4096

typedef short v8s __attribute__((ext_vector_type(8)));
typedef float v4f __attribute__((ext_vector_type(4)));
typedef _Float16 v2h __attribute__((ext_vector_type(2)));

__device__ __forceinline__ short f2bf(float f) {
  __hip_bfloat16 h = __float2bfloat16(f);
  return *reinterpret_cast<short*>(&h);
}

// pack two f32 -> packed bf16 dword, single instruction
__device__ __forceinline__ unsigned cvt_pk_bf16(float lo, float hi) {
  unsigned r;
  asm volatile("v_cvt_pk_bf16_f32 %0, %1, %2" : "=v"(r) : "v"(lo), "v"(hi));
  return r;
}

__device__ __forceinline__ v2h pk2h(float a, float b) {
  return __builtin_bit_cast(v2h, __builtin_amdgcn_cvt_pkrtz(a, b));
}
__device__ __forceinline__ float fdot2(v2h a, v2h b, float c) {
  return __builtin_amdgcn_fdot2(a, b, c, false);
}

// --- kernel 0: WCd[i] = sum_{j != i} AW[i][j] * (sum_k alphas[k]*clip[j][k]) ---
__global__ void k_prep(const float* __restrict__ AW, const float* __restrict__ alphas,
                       const float* __restrict__ clip, float* __restrict__ WCd) {
  __shared__ float cd[DZ];
  int j = threadIdx.x;
  float s = 0.f;
  for (int k = 0; k < DB; ++k) s = fmaf(alphas[k], clip[j * DB + k], s);
  cd[j] = s;
  __syncthreads();
  float acc = 0.f;
  for (int jj = 0; jj < DZ; ++jj)
    if (jj != j) acc = fmaf(AW[j * DZ + jj], cd[jj], acc);
  WCd[j] = acc;
}

// --- kernel 1: U[t][i] = h[i] - WCd[i] + sum_s C[i][s]*inp[t][s] (t-major) ---
__global__ void k_u(const float* __restrict__ inp, const float* __restrict__ h,
                    const float* __restrict__ C, const float* __restrict__ WCd,
                    float* __restrict__ U) {
  int gid = blockIdx.x * blockDim.x + threadIdx.x;
  int t = gid >> 7, i = gid & 127;
  float u = h[i] - WCd[i];
  const float4* c4 = (const float4*)(C + i * DSIN);
  const float4* i4 = (const float4*)(inp + (size_t)t * DSIN);
#pragma unroll
  for (int s = 0; s < 8; ++s) {
    float4 cv = c4[s], iv = i4[s];
    u = fmaf(cv.x, iv.x, u);
    u = fmaf(cv.y, iv.y, u);
    u = fmaf(cv.z, iv.z, u);
    u = fmaf(cv.w, iv.w, u);
  }
  U[gid] = u;
}

// --- kernel 2: sequential scan, ONE BATCH PER WAVE, no barriers.
// 256-thread blocks (4 waves = 4 independent batches), launch_bounds(256,1)
// -> VGPR cap 512, no spill (round 8's 512-thread version was capped at 128
// VGPRs and spilled W to scratch: +5.4GB FETCH, 2.5x slower).
// Lane l owns dims (2l, 2l+1). g exchange: intra-wave LDS write+readback
// (DS pipe in-order per wave; wave lockstep -> no barrier, no double buffer).
// W/theta/clip/alpha/g packed f16; accumulation via v_dot2_f32_f16 (f32 acc). ---
__global__ __launch_bounds__(256, 1) void k_scan(
    const float* __restrict__ z0, const float* __restrict__ AW,
    const float* __restrict__ thetas, const float* __restrict__ alphas,
    const float* __restrict__ clip, const float* __restrict__ U,
    unsigned* __restrict__ Z32) {
  __shared__ unsigned gsh[4][64];  // per-wave 256 B
  const int wv = threadIdx.x >> 6, l = threadIdx.x & 63;
  const int b = blockIdx.x * 4 + wv;
  const int r0 = 2 * l, r1 = r0 + 1;

  // W rows r0,r1 as packed f16 pairs (cols 2j,2j+1); diagonal zeroed branchlessly
  v2h w0[64], w1[64];
#pragma unroll
  for (int j = 0; j < 64; ++j) {
    float2 a0 = *(const float2*)(AW + (size_t)r0 * DZ + 2 * j);
    float2 a1 = *(const float2*)(AW + (size_t)r1 * DZ + 2 * j);
    float x0 = (j == l) ? 0.f : a0.x;  // col 2j   == r0 iff j==l
    float y1 = (j == l) ? 0.f : a1.y;  // col 2j+1 == r1 iff j==l
    w0[j] = pk2h(x0, a0.y);
    w1[j] = pk2h(a1.x, y1);
  }
  const float ad0 = AW[(size_t)r0 * DZ + r0], ad1 = AW[(size_t)r1 * DZ + r1];

  v2h th0[16], th1[16], nc0[16], nc1[16];
  int al[16];  // packed f16 (-0.82*alpha), wave-uniform -> SGPR via readfirstlane
#pragma unroll
  for (int k = 0; k < 16; ++k) {
    th0[k] = pk2h(thetas[r0 * DB + 2 * k], thetas[r0 * DB + 2 * k + 1]);
    th1[k] = pk2h(thetas[r1 * DB + 2 * k], thetas[r1 * DB + 2 * k + 1]);
    nc0[k] = pk2h(-clip[r0 * DB + 2 * k], -clip[r0 * DB + 2 * k + 1]);
    nc1[k] = pk2h(-clip[r1 * DB + 2 * k], -clip[r1 * DB + 2 * k + 1]);
    al[k] = __builtin_amdgcn_readfirstlane(__builtin_bit_cast(
        int, pk2h(-0.82f * alphas[2 * k], -0.82f * alphas[2 * k + 1])));
  }

  float zA = z0[b * DZ + r0], zB = z0[b * DZ + r1];
  float2 uc = *(const float2*)(U + r0);  // t = 0
  unsigned* zp = Z32 + (size_t)b * 64 + l;
  const v2h zero2 = pk2h(0.f, 0.f);
  const uint4* g4 = (const uint4*)gsh[wv];

#pragma unroll 1
  for (int t = 0; t < TT; ++t) {
    float2 un = *(const float2*)(U + (size_t)((t + 1) & (TT - 1)) * DZ + r0);
    // basis: g_r = sum_k (-0.82 a_k) * clamp(z_r - th_rk, -c_rk, 0), packed f16
    v2h za2 = pk2h(zA, zA), zb2 = pk2h(zB, zB);
    float g0 = 0.f, g1 = 0.f;
#pragma unroll
    for (int k = 0; k < 16; ++k) {
      v2h d0 = __builtin_elementwise_min(
          __builtin_elementwise_max(za2 - th0[k], nc0[k]), zero2);
      v2h d1 = __builtin_elementwise_min(
          __builtin_elementwise_max(zb2 - th1[k], nc1[k]), zero2);
      g0 = fdot2(__builtin_bit_cast(v2h, al[k]), d0, g0);
      g1 = fdot2(__builtin_bit_cast(v2h, al[k]), d1, g1);
    }
    // intra-wave exchange (no barrier: single-wave lockstep + in-order DS pipe)
    gsh[wv][l] = __builtin_bit_cast(unsigned, pk2h(g0, g1));
    // matvec rows r0,r1: 64 packed-f16 g dwords, broadcast reads, f32 acc
    float m0a = 0.f, m0b = 0.f, m1a = 0.f, m1b = 0.f;
#pragma unroll
    for (int r = 0; r < 16; ++r) {
      uint4 q = g4[r];
      v2h gA = __builtin_bit_cast(v2h, q.x), gB = __builtin_bit_cast(v2h, q.y);
      v2h gC = __builtin_bit_cast(v2h, q.z), gD = __builtin_bit_cast(v2h, q.w);
      m0a = fdot2(w0[4 * r + 0], gA, m0a);
      m1a = fdot2(w1[4 * r + 0], gA, m1a);
      m0b = fdot2(w0[4 * r + 1], gB, m0b);
      m1b = fdot2(w1[4 * r + 1], gB, m1b);
      m0a = fdot2(w0[4 * r + 2], gC, m0a);
      m1a = fdot2(w1[4 * r + 2], gC, m1a);
      m0b = fdot2(w0[4 * r + 3], gD, m0b);
      m1b = fdot2(w1[4 * r + 3], gD, m1b);
    }
    zA = fmaf(zA, ad0, (m0a + m0b) + uc.x);
    zB = fmaf(zB, ad1, (m1a + m1b) + uc.y);
    uc = un;
    zp[(size_t)t * (NB * 64)] = cvt_pk_bf16(zA, zB);  // coalesced dword store
  }
}

// --- kernel 3: out = Z(bf16, 262144x128) @ B_obs(128x64) via MFMA 16x16x32 bf16 ---
__global__ __launch_bounds__(256) void k_obs(const short* __restrict__ Z,
                                             const float* __restrict__ Bo,
                                             float* __restrict__ out) {
  const int lane = threadIdx.x & 63;
  const int wv = threadIdx.x >> 6;
  const int rl = lane & 15;  // A row / C col index
  const int g = lane >> 4;   // k-group

  v8s bfr[4][4];
#pragma unroll
  for (int nt = 0; nt < 4; ++nt) {
#pragma unroll
    for (int ks = 0; ks < 4; ++ks) {
      v8s f;
#pragma unroll
      for (int m = 0; m < 8; ++m) {
        int k = ks * 32 + g * 8 + m;
        f[m] = f2bf(Bo[k * DX + nt * 16 + rl]);
      }
      bfr[nt][ks] = f;
    }
  }

#pragma unroll
  for (int it = 0; it < 4; ++it) {
    const int r0 = blockIdx.x * 256 + it * 64 + wv * 16;
    const short* zrow = Z + (size_t)(r0 + rl) * DZ;
    v8s afr[4];
#pragma unroll
    for (int ks = 0; ks < 4; ++ks)
      afr[ks] = *(const v8s*)(zrow + ks * 32 + g * 8);
    v4f acc[4];
#pragma unroll
    for (int nt = 0; nt < 4; ++nt) acc[nt] = (v4f){0.f, 0.f, 0.f, 0.f};
#pragma unroll
    for (int nt = 0; nt < 4; ++nt) {
#pragma unroll
      for (int ks = 0; ks < 4; ++ks)
        acc[nt] = __builtin_amdgcn_mfma_f32_16x16x32_bf16(afr[ks], bfr[nt][ks], acc[nt], 0, 0, 0);
    }
#pragma unroll
    for (int nt = 0; nt < 4; ++nt) {
#pragma unroll
      for (int q = 0; q < 4; ++q)
        out[(size_t)(r0 + g * 4 + q) * DX + nt * 16 + rl] = acc[nt][q];
    }
  }
}

extern "C" void kernel_launch(void* const* d_in, const int* in_sizes, int n_in,
                              void* d_out, int out_size, void* d_ws, size_t ws_size,
                              hipStream_t stream) {
  const float* z0 = (const float*)d_in[0];
  const float* inp = (const float*)d_in[1];
  const float* AW = (const float*)d_in[2];
  const float* h = (const float*)d_in[3];
  const float* thetas = (const float*)d_in[4];
  const float* alphas = (const float*)d_in[5];
  const float* clip = (const float*)d_in[6];
  const float* C = (const float*)d_in[7];
  const float* Bo = (const float*)d_in[8];
  float* out = (float*)d_out;

  char* ws = (char*)d_ws;
  float* WCd = (float*)ws;                               // 512 B
  float* U = (float*)(ws + 1024);                        // TT*128 f32 = 2 MiB
  short* Z = (short*)(ws + 1024 + (size_t)TT * DZ * 4);  // TT*64*128 bf16 = 64 MiB

  k_prep<<<1, 128, 0, stream>>>(AW, alphas, clip, WCd);
  k_u<<<(TT * DZ) / 256, 256, 0, stream>>>(inp, h, C, WCd, U);
  k_scan<<<NB / 4, 256, 0, stream>>>(z0, AW, thetas, alphas, clip, U, (unsigned*)Z);
  k_obs<<<(TT * NB) / 256, 256, 0, stream>>>(Z, Bo, out);
}

// Round 10
// 1585.107 us; speedup vs baseline: 3.2031x; 1.9284x over previous
//
#include <hip/hip_runtime.h>
#include <hip/hip_bf16.h>
#include <hip/hip_fp16.h>

#define DZ 128
#define DB 32
#define DSIN 32
#define DX 64
#define NB 64
#define TT 4096

typedef short v8s __attribute__((ext_vector_type(8)));
typedef float v4f __attribute__((ext_vector_type(4)));
typedef _Float16 v2h __attribute__((ext_vector_type(2)));

// sum with xor-1 partner lane via DPP quad_perm [1,0,3,2] (VALU pipe, no LDS)
__device__ __forceinline__ float pair_sum(float x) {
  int xi = __builtin_bit_cast(int, x);
  int yi = __builtin_amdgcn_mov_dpp(xi, 0xB1, 0xF, 0xF, true);
  return x + __builtin_bit_cast(float, yi);
}

__device__ __forceinline__ short f2bf(float f) {
  __hip_bfloat16 h = __float2bfloat16(f);
  return *reinterpret_cast<short*>(&h);
}

__device__ __forceinline__ v2h pk2h(float a, float b) {
  return __builtin_bit_cast(v2h, __builtin_amdgcn_cvt_pkrtz(a, b));
}
__device__ __forceinline__ float fdot2(v2h a, v2h b, float c) {
  return __builtin_amdgcn_fdot2(a, b, c, false);
}

// --- kernel 0: WCd[i] = sum_{j != i} AW[i][j] * (sum_k alphas[k]*clip[j][k]) ---
__global__ void k_prep(const float* __restrict__ AW, const float* __restrict__ alphas,
                       const float* __restrict__ clip, float* __restrict__ WCd) {
  __shared__ float cd[DZ];
  int j = threadIdx.x;
  float s = 0.f;
  for (int k = 0; k < DB; ++k) s = fmaf(alphas[k], clip[j * DB + k], s);
  cd[j] = s;
  __syncthreads();
  float acc = 0.f;
  for (int jj = 0; jj < DZ; ++jj)
    if (jj != j) acc = fmaf(AW[j * DZ + jj], cd[jj], acc);
  WCd[j] = acc;
}

// --- kernel 1: UT[i][t] = h[i] - WCd[i] + sum_s C[i][s]*inp[t][s]  (transposed) ---
__global__ void k_u(const float* __restrict__ inp, const float* __restrict__ h,
                    const float* __restrict__ C, const float* __restrict__ WCd,
                    float* __restrict__ UT) {
  int gid = blockIdx.x * blockDim.x + threadIdx.x;  // 128 * 1024 threads
  int i = gid >> 10;
  int t0 = (gid & 1023) * 4;
  float base = h[i] - WCd[i];
  const float4* c4 = (const float4*)(C + i * DSIN);
  float4 cv[8];
#pragma unroll
  for (int s = 0; s < 8; ++s) cv[s] = c4[s];
  float out[4];
#pragma unroll
  for (int tt = 0; tt < 4; ++tt) {
    const float4* i4 = (const float4*)(inp + (size_t)(t0 + tt) * DSIN);
    float u = base;
#pragma unroll
    for (int s = 0; s < 8; ++s) {
      float4 iv = i4[s];
      u = fmaf(cv[s].x, iv.x, u);
      u = fmaf(cv[s].y, iv.y, u);
      u = fmaf(cv[s].z, iv.z, u);
      u = fmaf(cv[s].w, iv.w, u);
    }
    out[tt] = u;
  }
  *(float4*)(UT + (size_t)i * TT + t0) = make_float4(out[0], out[1], out[2], out[3]);
}

// --- kernel 2: sequential scan. One block per batch, 256 threads = 2 lanes/dim
// (round-2 structure) but ALL narrow math in packed f16 via v_dot2_f32_f16:
//  - basis split by lane-half (8 packed iters, 32 inst)
//  - g exchanged as packed-f16 dwords (64 dwords; 8 ds_read_b128 per lane)
//  - matvec = 32 fdot2 per lane, no unpack (round 4's mistake)
// f32 only for z, u, adiag. f16 numerics validated rounds 8/9 (absmax 4.0). ---
__global__ __launch_bounds__(256, 1) void k_scan(
    const float* __restrict__ z0, const float* __restrict__ AW,
    const float* __restrict__ thetas, const float* __restrict__ alphas,
    const float* __restrict__ clip, const float* __restrict__ UT,
    short* __restrict__ Z) {
  __shared__ __align__(16) unsigned gpk[2][64];  // packed f16 g, double-buffered
  const int b = blockIdx.x;
  const int tid = threadIdx.x;
  const int i = tid >> 1, hh = tid & 1;
  const int c0 = hh * 64;

  // W row i, cols [c0, c0+64) as 32 packed-f16 pairs; diagonal zeroed branchlessly
  v2h w[32];
#pragma unroll
  for (int j = 0; j < 32; ++j) {
    float2 a = *(const float2*)(AW + (size_t)i * DZ + c0 + 2 * j);
    float x = (c0 + 2 * j == i) ? 0.f : a.x;
    float y = (c0 + 2 * j + 1 == i) ? 0.f : a.y;
    w[j] = pk2h(x, y);
  }
  const float adiag = AW[(size_t)i * DZ + i];

  // basis: this lane covers ks [hh*16, hh*16+16) as 8 packed pairs
  v2h th[8], nc[8], al[8];
#pragma unroll
  for (int m = 0; m < 8; ++m) {
    int k = hh * 16 + 2 * m;
    th[m] = pk2h(thetas[i * DB + k], thetas[i * DB + k + 1]);
    nc[m] = pk2h(-clip[i * DB + k], -clip[i * DB + k + 1]);
    al[m] = pk2h(-0.82f * alphas[k], -0.82f * alphas[k + 1]);
  }

  float z = z0[b * DZ + i];
  const float4* up = (const float4*)(UT + (size_t)i * TT);
  float4 ug = up[0];
  short* zp = Z + b * DZ + i;
  const v2h zero2 = pk2h(0.f, 0.f);

#pragma unroll 1
  for (int tg = 0; tg < TT / 4; ++tg) {
    float4 ugn = up[(tg + 1 < TT / 4) ? tg + 1 : tg];  // prefetch next group
    float uarr[4] = {ug.x, ug.y, ug.z, ug.w};
#pragma unroll
    for (int q = 0; q < 4; ++q) {
      unsigned* gq = gpk[q & 1];
      // basis partial over this lane's 16 ks (packed f16, f32 acc)
      v2h z2 = pk2h(z, z);
      float g0 = 0.f;
#pragma unroll
      for (int m = 0; m < 8; ++m) {
        v2h d = __builtin_elementwise_min(
            __builtin_elementwise_max(z2 - th[m], nc[m]), zero2);
        g0 = fdot2(al[m], d, g0);
      }
      float gi = pair_sum(g0);  // combine hh halves -> full g_i on both lanes
      // lane 4d packs (g_2d, g_2d+1): grab dim-partner via quad_perm [2,3,2,3]
      int pi = __builtin_amdgcn_mov_dpp(__builtin_bit_cast(int, gi), 0xEE, 0xF, 0xF, true);
      unsigned pk = __builtin_bit_cast(unsigned, pk2h(gi, __builtin_bit_cast(float, pi)));
      if ((tid & 3) == 0) gq[tid >> 2] = pk;
      // drain LDS write, then barrier (no vmcnt drain: Z stores/U loads keep flying)
      asm volatile("s_waitcnt lgkmcnt(0)\n\ts_barrier" ::: "memory");

      // matvec half: m_i = sum_{cols c0..c0+63} W[i][c]*g[c]; 8 x ds_read_b128
      const uint4* g4 = (const uint4*)(gq + hh * 32);
      float m0 = 0.f, m1 = 0.f, m2 = 0.f, m3 = 0.f;
#pragma unroll
      for (int r = 0; r < 8; ++r) {
        uint4 qd = g4[r];
        m0 = fdot2(w[4 * r + 0], __builtin_bit_cast(v2h, qd.x), m0);
        m1 = fdot2(w[4 * r + 1], __builtin_bit_cast(v2h, qd.y), m1);
        m2 = fdot2(w[4 * r + 2], __builtin_bit_cast(v2h, qd.z), m2);
        m3 = fdot2(w[4 * r + 3], __builtin_bit_cast(v2h, qd.w), m3);
      }
      float mm = pair_sum((m0 + m1) + (m2 + m3));
      z = fmaf(z, adiag, mm + uarr[q]);
      if (hh == 0) zp[(size_t)(tg * 4 + q) * (NB * DZ)] = f2bf(z);
    }
    ug = ugn;
  }
}

// --- kernel 3: out = Z(bf16, 262144x128) @ B_obs(128x64) via MFMA 16x16x32 bf16 ---
__global__ __launch_bounds__(256) void k_obs(const short* __restrict__ Z,
                                             const float* __restrict__ Bo,
                                             float* __restrict__ out) {
  const int lane = threadIdx.x & 63;
  const int wv = threadIdx.x >> 6;
  const int rl = lane & 15;  // A row / C col index
  const int g = lane >> 4;   // k-group

  v8s bfr[4][4];
#pragma unroll
  for (int nt = 0; nt < 4; ++nt) {
#pragma unroll
    for (int ks = 0; ks < 4; ++ks) {
      v8s f;
#pragma unroll
      for (int m = 0; m < 8; ++m) {
        int k = ks * 32 + g * 8 + m;
        f[m] = f2bf(Bo[k * DX + nt * 16 + rl]);
      }
      bfr[nt][ks] = f;
    }
  }

#pragma unroll
  for (int it = 0; it < 4; ++it) {
    const int r0 = blockIdx.x * 256 + it * 64 + wv * 16;
    const short* zrow = Z + (size_t)(r0 + rl) * DZ;
    v8s afr[4];
#pragma unroll
    for (int ks = 0; ks < 4; ++ks)
      afr[ks] = *(const v8s*)(zrow + ks * 32 + g * 8);
    v4f acc[4];
#pragma unroll
    for (int nt = 0; nt < 4; ++nt) acc[nt] = (v4f){0.f, 0.f, 0.f, 0.f};
#pragma unroll
    for (int nt = 0; nt < 4; ++nt) {
#pragma unroll
      for (int ks = 0; ks < 4; ++ks)
        acc[nt] = __builtin_amdgcn_mfma_f32_16x16x32_bf16(afr[ks], bfr[nt][ks], acc[nt], 0, 0, 0);
    }
#pragma unroll
    for (int nt = 0; nt < 4; ++nt) {
#pragma unroll
      for (int q = 0; q < 4; ++q)
        out[(size_t)(r0 + g * 4 + q) * DX + nt * 16 + rl] = acc[nt][q];
    }
  }
}

extern "C" void kernel_launch(void* const* d_in, const int* in_sizes, int n_in,
                              void* d_out, int out_size, void* d_ws, size_t ws_size,
                              hipStream_t stream) {
  const float* z0 = (const float*)d_in[0];
  const float* inp = (const float*)d_in[1];
  const float* AW = (const float*)d_in[2];
  const float* h = (const float*)d_in[3];
  const float* thetas = (const float*)d_in[4];
  const float* alphas = (const float*)d_in[5];
  const float* clip = (const float*)d_in[6];
  const float* C = (const float*)d_in[7];
  const float* Bo = (const float*)d_in[8];
  float* out = (float*)d_out;

  char* ws = (char*)d_ws;
  float* WCd = (float*)ws;                                 // 512 B
  float* UT = (float*)(ws + 1024);                         // 128*TT f32 = 2 MiB
  short* Z = (short*)(ws + 1024 + (size_t)TT * DZ * 4);    // TT*64*128 bf16 = 64 MiB

  k_prep<<<1, 128, 0, stream>>>(AW, alphas, clip, WCd);
  k_u<<<(DZ * TT / 4) / 256, 256, 0, stream>>>(inp, h, C, WCd, UT);
  k_scan<<<NB, 256, 0, stream>>>(z0, AW, thetas, alphas, clip, UT, Z);
  k_obs<<<(TT * NB) / 256, 256, 0, stream>>>(Z, Bo, out);
}

// Round 11
// 1462.289 us; speedup vs baseline: 3.4721x; 1.0840x over previous
//
#include <hip/hip_runtime.h>
#include <hip/hip_bf16.h>
#include <hip/hip_fp16.h>

#define DZ 128
#define DB 32
#define DSIN 32
#define DX 64
#define NB 64
#define TT 4096

typedef short v8s __attribute__((ext_vector_type(8)));
typedef float v4f __attribute__((ext_vector_type(4)));
typedef _Float16 v2h __attribute__((ext_vector_type(2)));

// quad butterfly stages via DPP quad_perm (VALU pipe, intra-quad)
__device__ __forceinline__ float dpp_xor1(float x) {
  int y = __builtin_amdgcn_mov_dpp(__builtin_bit_cast(int, x), 0xB1, 0xF, 0xF, true);
  return __builtin_bit_cast(float, y);
}
__device__ __forceinline__ float dpp_xor2(float x) {
  int y = __builtin_amdgcn_mov_dpp(__builtin_bit_cast(int, x), 0x4E, 0xF, 0xF, true);
  return __builtin_bit_cast(float, y);
}

__device__ __forceinline__ short f2bf(float f) {
  __hip_bfloat16 h = __float2bfloat16(f);
  return *reinterpret_cast<short*>(&h);
}

__device__ __forceinline__ v2h pk2h(float a, float b) {
  return __builtin_bit_cast(v2h, __builtin_amdgcn_cvt_pkrtz(a, b));
}
__device__ __forceinline__ float fdot2(v2h a, v2h b, float c) {
  return __builtin_amdgcn_fdot2(a, b, c, false);
}

// --- kernel 0: WCd[i] = sum_{j != i} AW[i][j] * (sum_k alphas[k]*clip[j][k]) ---
__global__ void k_prep(const float* __restrict__ AW, const float* __restrict__ alphas,
                       const float* __restrict__ clip, float* __restrict__ WCd) {
  __shared__ float cd[DZ];
  int j = threadIdx.x;
  float s = 0.f;
  for (int k = 0; k < DB; ++k) s = fmaf(alphas[k], clip[j * DB + k], s);
  cd[j] = s;
  __syncthreads();
  float acc = 0.f;
  for (int jj = 0; jj < DZ; ++jj)
    if (jj != j) acc = fmaf(AW[j * DZ + jj], cd[jj], acc);
  WCd[j] = acc;
}

// --- kernel 1: UT[i][t] = h[i] - WCd[i] + sum_s C[i][s]*inp[t][s]  (transposed) ---
__global__ void k_u(const float* __restrict__ inp, const float* __restrict__ h,
                    const float* __restrict__ C, const float* __restrict__ WCd,
                    float* __restrict__ UT) {
  int gid = blockIdx.x * blockDim.x + threadIdx.x;  // 128 * 1024 threads
  int i = gid >> 10;
  int t0 = (gid & 1023) * 4;
  float base = h[i] - WCd[i];
  const float4* c4 = (const float4*)(C + i * DSIN);
  float4 cv[8];
#pragma unroll
  for (int s = 0; s < 8; ++s) cv[s] = c4[s];
  float out[4];
#pragma unroll
  for (int tt = 0; tt < 4; ++tt) {
    const float4* i4 = (const float4*)(inp + (size_t)(t0 + tt) * DSIN);
    float u = base;
#pragma unroll
    for (int s = 0; s < 8; ++s) {
      float4 iv = i4[s];
      u = fmaf(cv[s].x, iv.x, u);
      u = fmaf(cv[s].y, iv.y, u);
      u = fmaf(cv[s].z, iv.z, u);
      u = fmaf(cv[s].w, iv.w, u);
    }
    out[tt] = u;
  }
  *(float4*)(UT + (size_t)i * TT + t0) = make_float4(out[0], out[1], out[2], out[3]);
}

// --- kernel 2: sequential scan. One block per batch, 512 threads = 4 lanes/dim
// (quad s=tid&3 splits basis-k 4-way and matvec-cols 4-way). Quad combines via
// 2 DPP butterfly stages. g stored to LDS as f16 (ds_write_b16, no pack path),
// read back packed for v_dot2_f32_f16. 8 waves -> 2/SIMD doubles issue BW;
// per-lane: 4 packed-k basis, 4 ds_read_b128, 16 fdot2 matvec. ---
__global__ __launch_bounds__(512, 1) void k_scan(
    const float* __restrict__ z0, const float* __restrict__ AW,
    const float* __restrict__ thetas, const float* __restrict__ alphas,
    const float* __restrict__ clip, const float* __restrict__ UT,
    short* __restrict__ Z) {
  __shared__ __align__(16) _Float16 gsh[2][DZ];  // f16 g, double-buffered, 512 B
  const int b = blockIdx.x;
  const int tid = threadIdx.x;
  const int i = tid >> 2, s = tid & 3;
  const int c0 = 32 * s;

  // W row i, cols [c0, c0+32) as 16 packed-f16 pairs; diagonal zeroed branchlessly
  v2h w[16];
#pragma unroll
  for (int j = 0; j < 16; ++j) {
    float2 a = *(const float2*)(AW + (size_t)i * DZ + c0 + 2 * j);
    float x = (c0 + 2 * j == i) ? 0.f : a.x;
    float y = (c0 + 2 * j + 1 == i) ? 0.f : a.y;
    w[j] = pk2h(x, y);
  }
  const float adiag = AW[(size_t)i * DZ + i];

  // basis: this lane covers ks [8s, 8s+8) as 4 packed pairs
  v2h th[4], nc[4], al[4];
#pragma unroll
  for (int m = 0; m < 4; ++m) {
    int k = 8 * s + 2 * m;
    th[m] = pk2h(thetas[i * DB + k], thetas[i * DB + k + 1]);
    nc[m] = pk2h(-clip[i * DB + k], -clip[i * DB + k + 1]);
    al[m] = pk2h(-0.82f * alphas[k], -0.82f * alphas[k + 1]);
  }

  float z = z0[b * DZ + i];
  const float4* up = (const float4*)(UT + (size_t)i * TT);
  float4 ug = up[0];
  short* zp = Z + b * DZ + i;
  const v2h zero2 = pk2h(0.f, 0.f);

#pragma unroll 1
  for (int tg = 0; tg < TT / 4; ++tg) {
    float4 ugn = up[(tg + 1 < TT / 4) ? tg + 1 : tg];  // prefetch next group
    float uarr[4] = {ug.x, ug.y, ug.z, ug.w};
#pragma unroll
    for (int q = 0; q < 4; ++q) {
      _Float16* gq = gsh[q & 1];  // t parity == q parity (4 steps per tg)
      // basis partial over this lane's 8 ks (packed f16, f32 acc, 2 accumulators)
      v2h z2 = pk2h(z, z);
      float g0 = 0.f, g1 = 0.f;
#pragma unroll
      for (int m = 0; m < 4; m += 2) {
        v2h d0 = __builtin_elementwise_min(
            __builtin_elementwise_max(z2 - th[m], nc[m]), zero2);
        v2h d1 = __builtin_elementwise_min(
            __builtin_elementwise_max(z2 - th[m + 1], nc[m + 1]), zero2);
        g0 = fdot2(al[m], d0, g0);
        g1 = fdot2(al[m + 1], d1, g1);
      }
      float gf = g0 + g1;
      gf += dpp_xor1(gf);
      gf += dpp_xor2(gf);  // full g_i on all 4 quad lanes
      _Float16 ghalf = (_Float16)gf;
      if (s == 0) gq[i] = ghalf;  // one ds_write_b16 (16 lanes/wave active)
      // drain LDS write, then barrier (no vmcnt drain: Z stores/U loads keep flying)
      asm volatile("s_waitcnt lgkmcnt(0)\n\ts_barrier" ::: "memory");

      // matvec quarter: cols [c0, c0+32) -> 4 ds_read_b128 + 16 fdot2
      const uint4* g4 = ((const uint4*)gq) + 4 * s;
      float m0 = 0.f, m1 = 0.f, m2 = 0.f, m3 = 0.f;
#pragma unroll
      for (int r = 0; r < 4; ++r) {
        uint4 qd = g4[r];
        m0 = fdot2(w[4 * r + 0], __builtin_bit_cast(v2h, qd.x), m0);
        m1 = fdot2(w[4 * r + 1], __builtin_bit_cast(v2h, qd.y), m1);
        m2 = fdot2(w[4 * r + 2], __builtin_bit_cast(v2h, qd.z), m2);
        m3 = fdot2(w[4 * r + 3], __builtin_bit_cast(v2h, qd.w), m3);
      }
      float mm = (m0 + m1) + (m2 + m3);
      mm += dpp_xor1(mm);
      mm += dpp_xor2(mm);  // full row-sum on all 4 quad lanes
      z = fmaf(z, adiag, mm + uarr[q]);
      if (s == 0) zp[(size_t)(tg * 4 + q) * (NB * DZ)] = f2bf(z);
    }
    ug = ugn;
  }
}

// --- kernel 3: out = Z(bf16, 262144x128) @ B_obs(128x64) via MFMA 16x16x32 bf16 ---
__global__ __launch_bounds__(256) void k_obs(const short* __restrict__ Z,
                                             const float* __restrict__ Bo,
                                             float* __restrict__ out) {
  const int lane = threadIdx.x & 63;
  const int wv = threadIdx.x >> 6;
  const int rl = lane & 15;  // A row / C col index
  const int g = lane >> 4;   // k-group

  v8s bfr[4][4];
#pragma unroll
  for (int nt = 0; nt < 4; ++nt) {
#pragma unroll
    for (int ks = 0; ks < 4; ++ks) {
      v8s f;
#pragma unroll
      for (int m = 0; m < 8; ++m) {
        int k = ks * 32 + g * 8 + m;
        f[m] = f2bf(Bo[k * DX + nt * 16 + rl]);
      }
      bfr[nt][ks] = f;
    }
  }

#pragma unroll
  for (int it = 0; it < 4; ++it) {
    const int r0 = blockIdx.x * 256 + it * 64 + wv * 16;
    const short* zrow = Z + (size_t)(r0 + rl) * DZ;
    v8s afr[4];
#pragma unroll
    for (int ks = 0; ks < 4; ++ks)
      afr[ks] = *(const v8s*)(zrow + ks * 32 + g * 8);
    v4f acc[4];
#pragma unroll
    for (int nt = 0; nt < 4; ++nt) acc[nt] = (v4f){0.f, 0.f, 0.f, 0.f};
#pragma unroll
    for (int nt = 0; nt < 4; ++nt) {
#pragma unroll
      for (int ks = 0; ks < 4; ++ks)
        acc[nt] = __builtin_amdgcn_mfma_f32_16x16x32_bf16(afr[ks], bfr[nt][ks], acc[nt], 0, 0, 0);
    }
#pragma unroll
    for (int nt = 0; nt < 4; ++nt) {
#pragma unroll
      for (int q = 0; q < 4; ++q)
        out[(size_t)(r0 + g * 4 + q) * DX + nt * 16 + rl] = acc[nt][q];
    }
  }
}

extern "C" void kernel_launch(void* const* d_in, const int* in_sizes, int n_in,
                              void* d_out, int out_size, void* d_ws, size_t ws_size,
                              hipStream_t stream) {
  const float* z0 = (const float*)d_in[0];
  const float* inp = (const float*)d_in[1];
  const float* AW = (const float*)d_in[2];
  const float* h = (const float*)d_in[3];
  const float* thetas = (const float*)d_in[4];
  const float* alphas = (const float*)d_in[5];
  const float* clip = (const float*)d_in[6];
  const float* C = (const float*)d_in[7];
  const float* Bo = (const float*)d_in[8];
  float* out = (float*)d_out;

  char* ws = (char*)d_ws;
  float* WCd = (float*)ws;                                 // 512 B
  float* UT = (float*)(ws + 1024);                         // 128*TT f32 = 2 MiB
  short* Z = (short*)(ws + 1024 + (size_t)TT * DZ * 4);    // TT*64*128 bf16 = 64 MiB

  k_prep<<<1, 128, 0, stream>>>(AW, alphas, clip, WCd);
  k_u<<<(DZ * TT / 4) / 256, 256, 0, stream>>>(inp, h, C, WCd, UT);
  k_scan<<<NB, 512, 0, stream>>>(z0, AW, thetas, alphas, clip, UT, Z);
  k_obs<<<(TT * NB) / 256, 256, 0, stream>>>(Z, Bo, out);
}